// Round 1
// baseline (486.877 us; speedup 1.0000x reference)
//
#include <hip/hip_runtime.h>

#define NN 16384
#define DD 256
#define ROW_WORDS 512  // NN/32

// ---------------- scatter edges into symmetric bitmap (SET semantics) ----------------
__global__ __launch_bounds__(256) void k_scatter(const int* __restrict__ ei,
                                                 unsigned int* __restrict__ bm,
                                                 int E) {
    int e = blockIdx.x * 256 + threadIdx.x;
    if (e >= E) return;
    int s = ei[e];
    int d = ei[E + e];
    atomicOr(bm + ((size_t)s << 9) + (d >> 5), 1u << (d & 31));
    atomicOr(bm + ((size_t)d << 9) + (s >> 5), 1u << (s & 31));
}

// ---------------- fused GEMM: out = x@Wu^T + bu + ba ; xa = x@Wa^T ----------------
// grid = (256, 8), block = 256. Tile 64 rows x 64 cols, K-step 32.
__global__ __launch_bounds__(256) void k_gemm(const float* __restrict__ x,
                                              const float* __restrict__ Wu,
                                              const float* __restrict__ bu,
                                              const float* __restrict__ Wa,
                                              const float* __restrict__ ba,
                                              float* __restrict__ out,
                                              float* __restrict__ xa) {
    __shared__ float As[32][68];  // [k][m], stride 68 floats = 272B (16B aligned)
    __shared__ float Bs[32][68];  // [k][n]

    const int t = threadIdx.x;
    const int tx = t & 15;        // col group 0..15
    const int ty = t >> 4;        // row group 0..15
    const int row0 = blockIdx.x * 64;
    const int col0 = blockIdx.y * 64;
    const bool is_upd = (col0 < DD);
    const float* B = is_upd ? (Wu + (size_t)col0 * DD)
                            : (Wa + (size_t)(col0 - DD) * DD);

    const int lrow = t >> 3;       // 0..31
    const int lk = (t & 7) << 2;   // 0,4,...,28

    float acc[4][4] = {{0.f, 0.f, 0.f, 0.f},
                       {0.f, 0.f, 0.f, 0.f},
                       {0.f, 0.f, 0.f, 0.f},
                       {0.f, 0.f, 0.f, 0.f}};

    for (int k0 = 0; k0 < DD; k0 += 32) {
        float4 a0 = *(const float4*)(x + (size_t)(row0 + lrow) * DD + k0 + lk);
        float4 a1 = *(const float4*)(x + (size_t)(row0 + lrow + 32) * DD + k0 + lk);
        float4 b0 = *(const float4*)(B + (size_t)lrow * DD + k0 + lk);
        float4 b1 = *(const float4*)(B + (size_t)(lrow + 32) * DD + k0 + lk);
        __syncthreads();  // previous inner loop done reading LDS
        As[lk + 0][lrow] = a0.x; As[lk + 1][lrow] = a0.y;
        As[lk + 2][lrow] = a0.z; As[lk + 3][lrow] = a0.w;
        As[lk + 0][lrow + 32] = a1.x; As[lk + 1][lrow + 32] = a1.y;
        As[lk + 2][lrow + 32] = a1.z; As[lk + 3][lrow + 32] = a1.w;
        Bs[lk + 0][lrow] = b0.x; Bs[lk + 1][lrow] = b0.y;
        Bs[lk + 2][lrow] = b0.z; Bs[lk + 3][lrow] = b0.w;
        Bs[lk + 0][lrow + 32] = b1.x; Bs[lk + 1][lrow + 32] = b1.y;
        Bs[lk + 2][lrow + 32] = b1.z; Bs[lk + 3][lrow + 32] = b1.w;
        __syncthreads();
#pragma unroll
        for (int kk = 0; kk < 32; ++kk) {
            float4 av = *(const float4*)&As[kk][ty << 2];
            float4 bv = *(const float4*)&Bs[kk][tx << 2];
            acc[0][0] += av.x * bv.x; acc[0][1] += av.x * bv.y;
            acc[0][2] += av.x * bv.z; acc[0][3] += av.x * bv.w;
            acc[1][0] += av.y * bv.x; acc[1][1] += av.y * bv.y;
            acc[1][2] += av.y * bv.z; acc[1][3] += av.y * bv.w;
            acc[2][0] += av.z * bv.x; acc[2][1] += av.z * bv.y;
            acc[2][2] += av.z * bv.z; acc[2][3] += av.z * bv.w;
            acc[3][0] += av.w * bv.x; acc[3][1] += av.w * bv.y;
            acc[3][2] += av.w * bv.z; acc[3][3] += av.w * bv.w;
        }
    }

    const int c = col0 + (tx << 2);
    if (is_upd) {
        float bx = bu[c + 0] + ba[c + 0];
        float by = bu[c + 1] + ba[c + 1];
        float bz = bu[c + 2] + ba[c + 2];
        float bw = bu[c + 3] + ba[c + 3];
#pragma unroll
        for (int i = 0; i < 4; ++i) {
            float4 v;
            v.x = acc[i][0] + bx; v.y = acc[i][1] + by;
            v.z = acc[i][2] + bz; v.w = acc[i][3] + bw;
            *(float4*)(out + (size_t)(row0 + (ty << 2) + i) * DD + c) = v;
        }
    } else {
#pragma unroll
        for (int i = 0; i < 4; ++i) {
            float4 v;
            v.x = acc[i][0]; v.y = acc[i][1]; v.z = acc[i][2]; v.w = acc[i][3];
            *(float4*)(xa + (size_t)(row0 + (ty << 2) + i) * DD + (c - DD)) = v;
        }
    }
}

// ---------------- gather: out[i] += sum_{j in neighbors(i)} xa[j] ----------------
// one block (256 threads) per row; thread t owns feature dim t.
__global__ __launch_bounds__(256) void k_gather(const unsigned int* __restrict__ bm,
                                                const float* __restrict__ xa,
                                                float* __restrict__ out) {
    const int row = blockIdx.x;
    const int t = threadIdx.x;
    const uint4* rbm = (const uint4*)(bm + ((size_t)row << 9));

    float acc = 0.f;
    uint4 w = rbm[0];
    for (int c = 0; c < 128; ++c) {
        uint4 wn;
        if (c < 127) wn = rbm[c + 1];
        else { wn.x = 0u; wn.y = 0u; wn.z = 0u; wn.w = 0u; }
        const int base = c << 7;  // c*4 words * 32 bits
        unsigned int b0 = w.x, b1 = w.y, b2 = w.z, b3 = w.w;
        while (b0) { int bit = __ffs(b0) - 1; b0 &= b0 - 1;
                     acc += xa[((size_t)(base + bit) << 8) + t]; }
        while (b1) { int bit = __ffs(b1) - 1; b1 &= b1 - 1;
                     acc += xa[((size_t)(base + 32 + bit) << 8) + t]; }
        while (b2) { int bit = __ffs(b2) - 1; b2 &= b2 - 1;
                     acc += xa[((size_t)(base + 64 + bit) << 8) + t]; }
        while (b3) { int bit = __ffs(b3) - 1; b3 &= b3 - 1;
                     acc += xa[((size_t)(base + 96 + bit) << 8) + t]; }
        w = wn;
    }
    out[((size_t)row << 8) + t] += acc;
}

extern "C" void kernel_launch(void* const* d_in, const int* in_sizes, int n_in,
                              void* d_out, int out_size, void* d_ws, size_t ws_size,
                              hipStream_t stream) {
    const float* x  = (const float*)d_in[0];
    const int*   ei = (const int*)d_in[1];
    const float* Wu = (const float*)d_in[2];
    const float* bu = (const float*)d_in[3];
    const float* Wa = (const float*)d_in[4];
    const float* ba = (const float*)d_in[5];
    float* out = (float*)d_out;

    const int E = in_sizes[1] / 2;

    unsigned int* bm = (unsigned int*)d_ws;                       // 32 MiB bitmap
    float* xa = (float*)((char*)d_ws + (size_t)NN * ROW_WORDS * 4);  // 16 MiB xa

    hipMemsetAsync(bm, 0, (size_t)NN * ROW_WORDS * sizeof(unsigned int), stream);
    k_scatter<<<(E + 255) / 256, 256, 0, stream>>>(ei, bm, E);
    dim3 ggrid(NN / 64, 512 / 64);
    k_gemm<<<ggrid, 256, 0, stream>>>(x, Wu, bu, Wa, ba, out, xa);
    k_gather<<<NN, 256, 0, stream>>>(bm, xa, out);
}

// Round 2
// 204.994 us; speedup vs baseline: 2.3751x; 2.3751x over previous
//
#include <hip/hip_runtime.h>

#define NN 16384
#define DD 256
#define ROW_WORDS 512  // NN/32
#define DEG_CAP 512

// ---------------- scatter edges into symmetric bitmap (SET semantics) ----------------
__global__ __launch_bounds__(256) void k_scatter(const int* __restrict__ ei,
                                                 unsigned int* __restrict__ bm,
                                                 int E) {
    int e = blockIdx.x * 256 + threadIdx.x;
    if (e >= E) return;
    int s = ei[e];
    int d = ei[E + e];
    atomicOr(bm + ((size_t)s << 9) + (d >> 5), 1u << (d & 31));
    atomicOr(bm + ((size_t)d << 9) + (s >> 5), 1u << (s & 31));
}

// ---------------- fused GEMM: out = x@Wu^T + bu + ba ; xa = x@Wa^T ----------------
// grid = (256, 8), block = 256. Tile 64 rows x 64 cols, K-step 32.
__global__ __launch_bounds__(256) void k_gemm(const float* __restrict__ x,
                                              const float* __restrict__ Wu,
                                              const float* __restrict__ bu,
                                              const float* __restrict__ Wa,
                                              const float* __restrict__ ba,
                                              float* __restrict__ out,
                                              float* __restrict__ xa) {
    __shared__ float As[32][68];  // [k][m]
    __shared__ float Bs[32][68];  // [k][n]

    const int t = threadIdx.x;
    const int tx = t & 15;
    const int ty = t >> 4;
    const int row0 = blockIdx.x * 64;
    const int col0 = blockIdx.y * 64;
    const bool is_upd = (col0 < DD);
    const float* B = is_upd ? (Wu + (size_t)col0 * DD)
                            : (Wa + (size_t)(col0 - DD) * DD);

    const int lrow = t >> 3;
    const int lk = (t & 7) << 2;

    float acc[4][4] = {{0.f, 0.f, 0.f, 0.f},
                       {0.f, 0.f, 0.f, 0.f},
                       {0.f, 0.f, 0.f, 0.f},
                       {0.f, 0.f, 0.f, 0.f}};

    for (int k0 = 0; k0 < DD; k0 += 32) {
        float4 a0 = *(const float4*)(x + (size_t)(row0 + lrow) * DD + k0 + lk);
        float4 a1 = *(const float4*)(x + (size_t)(row0 + lrow + 32) * DD + k0 + lk);
        float4 b0 = *(const float4*)(B + (size_t)lrow * DD + k0 + lk);
        float4 b1 = *(const float4*)(B + (size_t)(lrow + 32) * DD + k0 + lk);
        __syncthreads();
        As[lk + 0][lrow] = a0.x; As[lk + 1][lrow] = a0.y;
        As[lk + 2][lrow] = a0.z; As[lk + 3][lrow] = a0.w;
        As[lk + 0][lrow + 32] = a1.x; As[lk + 1][lrow + 32] = a1.y;
        As[lk + 2][lrow + 32] = a1.z; As[lk + 3][lrow + 32] = a1.w;
        Bs[lk + 0][lrow] = b0.x; Bs[lk + 1][lrow] = b0.y;
        Bs[lk + 2][lrow] = b0.z; Bs[lk + 3][lrow] = b0.w;
        Bs[lk + 0][lrow + 32] = b1.x; Bs[lk + 1][lrow + 32] = b1.y;
        Bs[lk + 2][lrow + 32] = b1.z; Bs[lk + 3][lrow + 32] = b1.w;
        __syncthreads();
#pragma unroll
        for (int kk = 0; kk < 32; ++kk) {
            float4 av = *(const float4*)&As[kk][ty << 2];
            float4 bv = *(const float4*)&Bs[kk][tx << 2];
            acc[0][0] += av.x * bv.x; acc[0][1] += av.x * bv.y;
            acc[0][2] += av.x * bv.z; acc[0][3] += av.x * bv.w;
            acc[1][0] += av.y * bv.x; acc[1][1] += av.y * bv.y;
            acc[1][2] += av.y * bv.z; acc[1][3] += av.y * bv.w;
            acc[2][0] += av.z * bv.x; acc[2][1] += av.z * bv.y;
            acc[2][2] += av.z * bv.z; acc[2][3] += av.z * bv.w;
            acc[3][0] += av.w * bv.x; acc[3][1] += av.w * bv.y;
            acc[3][2] += av.w * bv.z; acc[3][3] += av.w * bv.w;
        }
    }

    const int c = col0 + (tx << 2);
    if (is_upd) {
        float bx = bu[c + 0] + ba[c + 0];
        float by = bu[c + 1] + ba[c + 1];
        float bz = bu[c + 2] + ba[c + 2];
        float bw = bu[c + 3] + ba[c + 3];
#pragma unroll
        for (int i = 0; i < 4; ++i) {
            float4 v;
            v.x = acc[i][0] + bx; v.y = acc[i][1] + by;
            v.z = acc[i][2] + bz; v.w = acc[i][3] + bw;
            *(float4*)(out + (size_t)(row0 + (ty << 2) + i) * DD + c) = v;
        }
    } else {
#pragma unroll
        for (int i = 0; i < 4; ++i) {
            float4 v;
            v.x = acc[i][0]; v.y = acc[i][1]; v.z = acc[i][2]; v.w = acc[i][3];
            *(float4*)(xa + (size_t)(row0 + (ty << 2) + i) * DD + (c - DD)) = v;
        }
    }
}

// ---------------- gather: out[i] += sum_{j in nbr(i)} xa[j] ----------------
// 1 wave per row, 4 rows per block. Phase 1: bitmap -> LDS index list.
// Phase 2: lane owns dims 4l..4l+3 (float4); 8-way unrolled independent loads.
__device__ __forceinline__ void acc4(float4& a, const float4 b) {
    a.x += b.x; a.y += b.y; a.z += b.z; a.w += b.w;
}

__global__ __launch_bounds__(256) void k_gather(const unsigned int* __restrict__ bm,
                                                const float* __restrict__ xa,
                                                float* __restrict__ out) {
    __shared__ int list[4][DEG_CAP];
    __shared__ int cnt[4];

    const int t = threadIdx.x;
    const int wid = t >> 6;
    const int lane = t & 63;
    const int row = (blockIdx.x << 2) + wid;

    if (t < 4) cnt[t] = 0;
    __syncthreads();

    // phase 1: extract neighbor indices (each lane scans 2 uint4 = 256 bits)
    const uint4* rbm = (const uint4*)(bm + ((size_t)row << 9));
#pragma unroll
    for (int g = 0; g < 2; ++g) {
        const int q = lane * 2 + g;
        uint4 wv = rbm[q];
        const int base = q << 7;  // q * 128 bits
        unsigned int b;
        int bit, p;
        b = wv.x; while (b) { bit = __ffs(b) - 1; b &= b - 1;
            p = atomicAdd(&cnt[wid], 1); if (p < DEG_CAP) list[wid][p] = base + bit; }
        b = wv.y; while (b) { bit = __ffs(b) - 1; b &= b - 1;
            p = atomicAdd(&cnt[wid], 1); if (p < DEG_CAP) list[wid][p] = base + 32 + bit; }
        b = wv.z; while (b) { bit = __ffs(b) - 1; b &= b - 1;
            p = atomicAdd(&cnt[wid], 1); if (p < DEG_CAP) list[wid][p] = base + 64 + bit; }
        b = wv.w; while (b) { bit = __ffs(b) - 1; b &= b - 1;
            p = atomicAdd(&cnt[wid], 1); if (p < DEG_CAP) list[wid][p] = base + 96 + bit; }
    }
    __syncthreads();

    const int n = min(cnt[wid], DEG_CAP);
    const size_t col = (size_t)(lane << 2);

    float4 a0 = {0.f,0.f,0.f,0.f}, a1 = a0, a2 = a0, a3 = a0;
    float4 a4 = a0, a5 = a0, a6 = a0, a7 = a0;

    int i = 0;
    for (; i + 8 <= n; i += 8) {
        const int j0 = list[wid][i + 0], j1 = list[wid][i + 1];
        const int j2 = list[wid][i + 2], j3 = list[wid][i + 3];
        const int j4 = list[wid][i + 4], j5 = list[wid][i + 5];
        const int j6 = list[wid][i + 6], j7 = list[wid][i + 7];
        const float4 v0 = *(const float4*)(xa + (((size_t)j0) << 8) + col);
        const float4 v1 = *(const float4*)(xa + (((size_t)j1) << 8) + col);
        const float4 v2 = *(const float4*)(xa + (((size_t)j2) << 8) + col);
        const float4 v3 = *(const float4*)(xa + (((size_t)j3) << 8) + col);
        const float4 v4 = *(const float4*)(xa + (((size_t)j4) << 8) + col);
        const float4 v5 = *(const float4*)(xa + (((size_t)j5) << 8) + col);
        const float4 v6 = *(const float4*)(xa + (((size_t)j6) << 8) + col);
        const float4 v7 = *(const float4*)(xa + (((size_t)j7) << 8) + col);
        acc4(a0, v0); acc4(a1, v1); acc4(a2, v2); acc4(a3, v3);
        acc4(a4, v4); acc4(a5, v5); acc4(a6, v6); acc4(a7, v7);
    }
    for (; i < n; ++i) {
        const int j = list[wid][i];
        acc4(a0, *(const float4*)(xa + (((size_t)j) << 8) + col));
    }

    acc4(a0, a1); acc4(a2, a3); acc4(a4, a5); acc4(a6, a7);
    acc4(a0, a2); acc4(a4, a6);
    acc4(a0, a4);

    float4* po = (float4*)(out + (((size_t)row) << 8) + col);
    float4 o = *po;
    acc4(o, a0);
    *po = o;
}

extern "C" void kernel_launch(void* const* d_in, const int* in_sizes, int n_in,
                              void* d_out, int out_size, void* d_ws, size_t ws_size,
                              hipStream_t stream) {
    const float* x  = (const float*)d_in[0];
    const int*   ei = (const int*)d_in[1];
    const float* Wu = (const float*)d_in[2];
    const float* bu = (const float*)d_in[3];
    const float* Wa = (const float*)d_in[4];
    const float* ba = (const float*)d_in[5];
    float* out = (float*)d_out;

    const int E = in_sizes[1] / 2;

    unsigned int* bm = (unsigned int*)d_ws;                          // 32 MiB bitmap
    float* xa = (float*)((char*)d_ws + (size_t)NN * ROW_WORDS * 4);  // 16 MiB xa

    hipMemsetAsync(bm, 0, (size_t)NN * ROW_WORDS * sizeof(unsigned int), stream);
    k_scatter<<<(E + 255) / 256, 256, 0, stream>>>(ei, bm, E);
    dim3 ggrid(NN / 64, 512 / 64);
    k_gemm<<<ggrid, 256, 0, stream>>>(x, Wu, bu, Wa, ba, out, xa);
    k_gather<<<NN / 4, 256, 0, stream>>>(bm, xa, out);
}

// Round 3
// 126.132 us; speedup vs baseline: 3.8600x; 1.6252x over previous
//
#include <hip/hip_runtime.h>

#define NN 16384
#define DD 256
#define ROW_WORDS 512  // NN/32
#define GDEG 256
#define LDAP 40        // padded LDS row stride in bf16 elems (80 B)

typedef __attribute__((ext_vector_type(8))) __bf16 bf16x8;
typedef __attribute__((ext_vector_type(4))) float f32x4;

__device__ __forceinline__ unsigned short f2b(float f) {
    union { float f; unsigned int i; } v; v.f = f;
    unsigned int u = v.i;
    u = (u + 0x7fffu + ((u >> 16) & 1u)) >> 16;  // RTNE
    return (unsigned short)u;
}
__device__ __forceinline__ float b2f(unsigned short u) {
    union { unsigned int i; float f; } v; v.i = ((unsigned int)u) << 16; return v.f;
}

// ---------------- scatter edges into symmetric bitmap (SET semantics) ----------------
__global__ __launch_bounds__(256) void k_scatter(const int* __restrict__ ei,
                                                 unsigned int* __restrict__ bm,
                                                 int E) {
    int e = blockIdx.x * 256 + threadIdx.x;
    if (e >= E) return;
    int s = ei[e];
    int d = ei[E + e];
    atomicOr(bm + ((size_t)s << 9) + (d >> 5), 1u << (d & 31));
    atomicOr(bm + ((size_t)d << 9) + (s >> 5), 1u << (s & 31));
}

// ---------------- MFMA GEMM: out = x@Wu^T + bu + ba (cols 0-255)
//                            xab = bf16(x@Wa^T)      (cols 256-511)
// grid (128, 4), block 256 = 4 waves (2x2), tile 128x128, BK=32.
__global__ __launch_bounds__(256) void k_gemm(const float* __restrict__ x,
                                              const float* __restrict__ Wu,
                                              const float* __restrict__ bu,
                                              const float* __restrict__ Wa,
                                              const float* __restrict__ ba,
                                              float* __restrict__ out,
                                              unsigned short* __restrict__ xab) {
    __shared__ __align__(16) unsigned short Asu[128 * LDAP];
    __shared__ __align__(16) unsigned short Bsu[128 * LDAP];

    const int t = threadIdx.x;
    const int lane = t & 63;
    const int wid = t >> 6;
    const int wr = wid >> 1, wc = wid & 1;
    const int row0 = blockIdx.x * 128;
    const int col0 = blockIdx.y * 128;
    const bool is_upd = (col0 < DD);
    const float* Wsrc = is_upd ? (Wu + (size_t)col0 * DD)
                               : (Wa + (size_t)(col0 - DD) * DD);

    f32x4 acc[4][4] = {};
    bf16x8 av[4], bv[4];

    for (int k0 = 0; k0 < DD; k0 += 32) {
        float4 ga[4], gb[4];
#pragma unroll
        for (int i = 0; i < 4; ++i) {
            const int f = t + 256 * i;       // flat float4 id
            const int r = f >> 3;            // 0..127
            const int cb = f & 7;            // float4 within row
            ga[i] = *(const float4*)(x + (size_t)(row0 + r) * DD + k0 + cb * 4);
            gb[i] = *(const float4*)(Wsrc + (size_t)r * DD + k0 + cb * 4);
        }
        __syncthreads();  // previous iter's LDS reads done
#pragma unroll
        for (int i = 0; i < 4; ++i) {
            const int f = t + 256 * i;
            const int r = f >> 3;
            const int cb = f & 7;
            ushort4 ap, bp;
            ap.x = f2b(ga[i].x); ap.y = f2b(ga[i].y); ap.z = f2b(ga[i].z); ap.w = f2b(ga[i].w);
            bp.x = f2b(gb[i].x); bp.y = f2b(gb[i].y); bp.z = f2b(gb[i].z); bp.w = f2b(gb[i].w);
            *(ushort4*)(&Asu[r * LDAP + cb * 4]) = ap;
            *(ushort4*)(&Bsu[r * LDAP + cb * 4]) = bp;
        }
        __syncthreads();
#pragma unroll
        for (int fm = 0; fm < 4; ++fm) {
            uint4 ra = *(const uint4*)(&Asu[(wr * 64 + fm * 16 + (lane & 15)) * LDAP + (lane >> 4) * 8]);
            av[fm] = __builtin_bit_cast(bf16x8, ra);
        }
#pragma unroll
        for (int fn = 0; fn < 4; ++fn) {
            uint4 rb = *(const uint4*)(&Bsu[(wc * 64 + fn * 16 + (lane & 15)) * LDAP + (lane >> 4) * 8]);
            bv[fn] = __builtin_bit_cast(bf16x8, rb);
        }
#pragma unroll
        for (int fm = 0; fm < 4; ++fm)
#pragma unroll
            for (int fn = 0; fn < 4; ++fn)
                acc[fm][fn] = __builtin_amdgcn_mfma_f32_16x16x32_bf16(
                    av[fm], bv[fn], acc[fm][fn], 0, 0, 0);
    }

    // epilogue: C/D layout col = lane&15, row = (lane>>4)*4 + i
    const int gr0 = row0 + wr * 64 + ((lane >> 4) << 2);
    const int gcb = col0 + wc * 64 + (lane & 15);
    if (is_upd) {
#pragma unroll
        for (int fn = 0; fn < 4; ++fn) {
            const int c = gcb + fn * 16;
            const float bias = bu[c] + ba[c];
#pragma unroll
            for (int fm = 0; fm < 4; ++fm) {
                const int r = gr0 + fm * 16;
#pragma unroll
                for (int i = 0; i < 4; ++i)
                    out[(size_t)(r + i) * DD + c] = acc[fm][fn][i] + bias;
            }
        }
    } else {
#pragma unroll
        for (int fn = 0; fn < 4; ++fn) {
            const int c = gcb + fn * 16 - DD;
#pragma unroll
            for (int fm = 0; fm < 4; ++fm) {
                const int r = gr0 + fm * 16;
#pragma unroll
                for (int i = 0; i < 4; ++i)
                    xab[(size_t)(r + i) * DD + c] = f2b(acc[fm][fn][i]);
            }
        }
    }
}

// ---------------- gather: out[i] += sum_{j in nbr(i)} xa_bf16[j] ----------------
// 1 wave per row, 4 rows/block. Phase 1: bitmap -> LDS index list.
// Phase 2: lane owns dims 4l..4l+3 (ushort4); 16-deep unrolled loads.
__global__ __launch_bounds__(256) void k_gather(const unsigned int* __restrict__ bm,
                                                const unsigned short* __restrict__ xab,
                                                float* __restrict__ out) {
    __shared__ int list[4][GDEG];
    __shared__ int cnt[4];

    const int t = threadIdx.x;
    const int wid = t >> 6;
    const int lane = t & 63;
    const int row = (blockIdx.x << 2) + wid;

    if (t < 4) cnt[t] = 0;
    __syncthreads();

    const uint4* rbm = (const uint4*)(bm + ((size_t)row << 9));
#pragma unroll
    for (int g = 0; g < 2; ++g) {
        const int q = lane + 64 * g;  // coalesced
        uint4 wv = rbm[q];
        const int base = q << 7;
        unsigned int b;
        int bit, p;
        b = wv.x; while (b) { bit = __ffs(b) - 1; b &= b - 1;
            p = atomicAdd(&cnt[wid], 1); if (p < GDEG) list[wid][p] = base + bit; }
        b = wv.y; while (b) { bit = __ffs(b) - 1; b &= b - 1;
            p = atomicAdd(&cnt[wid], 1); if (p < GDEG) list[wid][p] = base + 32 + bit; }
        b = wv.z; while (b) { bit = __ffs(b) - 1; b &= b - 1;
            p = atomicAdd(&cnt[wid], 1); if (p < GDEG) list[wid][p] = base + 64 + bit; }
        b = wv.w; while (b) { bit = __ffs(b) - 1; b &= b - 1;
            p = atomicAdd(&cnt[wid], 1); if (p < GDEG) list[wid][p] = base + 96 + bit; }
    }
    __syncthreads();

    const int n = min(cnt[wid], GDEG);
    const int coff = lane << 2;  // ushort offset (dims 4l..4l+3)

    float4 a[8];
#pragma unroll
    for (int j = 0; j < 8; ++j) { a[j].x = 0.f; a[j].y = 0.f; a[j].z = 0.f; a[j].w = 0.f; }

    int i = 0;
    for (; i + 16 <= n; i += 16) {
        ushort4 v[16];
#pragma unroll
        for (int j = 0; j < 16; ++j) {
            const int idx = list[wid][i + j];
            v[j] = *(const ushort4*)(xab + (((size_t)idx) << 8) + coff);
        }
#pragma unroll
        for (int j = 0; j < 16; ++j) {
            float4& A = a[j & 7];
            A.x += b2f(v[j].x); A.y += b2f(v[j].y);
            A.z += b2f(v[j].z); A.w += b2f(v[j].w);
        }
    }
    for (; i < n; ++i) {
        const int idx = list[wid][i];
        ushort4 vv = *(const ushort4*)(xab + (((size_t)idx) << 8) + coff);
        a[0].x += b2f(vv.x); a[0].y += b2f(vv.y);
        a[0].z += b2f(vv.z); a[0].w += b2f(vv.w);
    }

#pragma unroll
    for (int j = 4; j < 8; ++j) {
        a[j - 4].x += a[j].x; a[j - 4].y += a[j].y;
        a[j - 4].z += a[j].z; a[j - 4].w += a[j].w;
    }
    a[0].x += a[1].x + a[2].x + a[3].x;
    a[0].y += a[1].y + a[2].y + a[3].y;
    a[0].z += a[1].z + a[2].z + a[3].z;
    a[0].w += a[1].w + a[2].w + a[3].w;

    float4* po = (float4*)(out + (((size_t)row) << 8) + coff);
    float4 o = *po;
    o.x += a[0].x; o.y += a[0].y; o.z += a[0].z; o.w += a[0].w;
    *po = o;
}

extern "C" void kernel_launch(void* const* d_in, const int* in_sizes, int n_in,
                              void* d_out, int out_size, void* d_ws, size_t ws_size,
                              hipStream_t stream) {
    const float* x  = (const float*)d_in[0];
    const int*   ei = (const int*)d_in[1];
    const float* Wu = (const float*)d_in[2];
    const float* bu = (const float*)d_in[3];
    const float* Wa = (const float*)d_in[4];
    const float* ba = (const float*)d_in[5];
    float* out = (float*)d_out;

    const int E = in_sizes[1] / 2;

    unsigned int* bm = (unsigned int*)d_ws;                                   // 32 MiB bitmap
    unsigned short* xab = (unsigned short*)((char*)d_ws + (size_t)NN * ROW_WORDS * 4);  // 8 MiB bf16 xa

    hipMemsetAsync(bm, 0, (size_t)NN * ROW_WORDS * sizeof(unsigned int), stream);
    k_scatter<<<(E + 255) / 256, 256, 0, stream>>>(ei, bm, E);
    dim3 ggrid(NN / 128, 4);
    k_gemm<<<ggrid, 256, 0, stream>>>(x, Wu, bu, Wa, ba, out, xab);
    k_gather<<<NN / 4, 256, 0, stream>>>(bm, xab, out);
}